// Round 7
// baseline (220.412 us; speedup 1.0000x reference)
//
#include <hip/hip_runtime.h>
#include <hip/hip_bf16.h>

// CIN round 7: barrier-free wave-owned-fi design, fully fused layers.
//
//  - Each wave owns fi = wid (mod 8). Softmax for one fi lives entirely in
//    the wave's registers (2 f0-halves x 32 k lanes); the 32x32x16 A-frag is
//    assembled with 4 shfl_xor(.,32) per fi. NO LDS A-tile, NO main-loop
//    barriers.
//  - F0 padded 40->48 => 3 K-steps per fi; pads have xk=0 (e=1, subtracted
//    from denom) and xv=0 (zero A contribution); B rows zero-padded too.
//  - One fused kernel: layer0 -> res in LDS (f32, atomicAdd reduce) ->
//    out[0:200] k-sum -> layer1 -> out[200:400]. No global res, no memset,
//    no global atomics.
// frag maps (validated R5/R6 in-situ): A[l&31][8*(l>>5)+i],
// B[8*(l>>5)+i][l&31], D: col=l&31, row=(r&3)+8*(r>>2)+4*(l>>5)

#define NF0  40
#define KD   32
#define NJ   200
#define NTHR 512
#define G0   120      // 40 fi * 3
#define G1   600      // 200 fi * 3

typedef short bf16x8 __attribute__((ext_vector_type(8)));
typedef float f32x16 __attribute__((ext_vector_type(16)));
typedef unsigned short u16;
typedef unsigned int   u32;

static __device__ __forceinline__ u16 f2bf(float f) {
    __hip_bfloat16 h = __float2bfloat16(f);
    return *reinterpret_cast<u16*>(&h);
}

// ---- pack: cw [f0*FI+fi, 200] -> bp frag-major, c'' = fi*48 + f0 (48-pad) ----
// bp[((nt*G + fi*3 + g)*64 + l)*8 + i] = B[c''=(fi*48)+(g*16+8*(l>>5)+i)][j=nt*32+(l&31)]
template<int FI>
__global__ __launch_bounds__(256)
void pack_b(const float* __restrict__ cw, u16* __restrict__ bp) {
    __shared__ u16 s[48][33];
    const int fi = blockIdx.x, nt = blockIdx.y;
    const int t = threadIdx.x;
    for (int idx = t; idx < 48 * 32; idx += 256) {
        int f0 = idx >> 5, jj = idx & 31, j = nt * 32 + jj;
        float v = (f0 < NF0 && j < NJ) ? cw[(size_t)(f0 * FI + fi) * NJ + j] : 0.f;
        s[f0][jj] = f2bf(v);
    }
    __syncthreads();
    if (t < 192) {
        const int g = t >> 6, l = t & 63;
        u16 v[8];
        #pragma unroll
        for (int i = 0; i < 8; ++i) v[i] = s[g * 16 + 8 * (l >> 5) + i][l & 31];
        constexpr int G = FI * 3;
        *reinterpret_cast<bf16x8*>(bp + ((size_t)(nt * G + fi * 3 + g) * 64 + l) * 8)
            = *reinterpret_cast<const bf16x8*>(v);
    }
}

// ---- fused CIN: grid 256 (1 batch/block), 8 waves ----
__global__ __launch_bounds__(NTHR, 2)
void cin_fused(const float* __restrict__ x0,
               const float* __restrict__ wq0, const float* __restrict__ wk0,
               const float* __restrict__ wv0,
               const float* __restrict__ wq1, const float* __restrict__ wk1,
               const float* __restrict__ wv1,
               const u16* __restrict__ bp0, const u16* __restrict__ bp1,
               float* __restrict__ out) {
    __shared__ float s_res[NJ][33];    // layer0 output, f32
    __shared__ float s_o1[224];
    const int tid = threadIdx.x, b = blockIdx.x;
    const int wid = tid >> 6, lane = tid & 63;
    const int sk = lane & 31, sh = lane >> 5;
    const bool hb = (lane >= 32);

    for (int i = tid; i < NJ * 33; i += NTHR) (&s_res[0][0])[i] = 0.f;
    if (tid < 224) s_o1[tid] = 0.f;

    float xkr[24], xvr[24];
    f32x16 acc[7];

    auto load_xw = [&](const float* wk, const float* wv) {
        #pragma unroll
        for (int m = 0; m < 24; ++m) {
            const int f0 = sh * 24 + m;
            if (f0 < NF0) {
                const float v = x0[(size_t)b * 1280 + f0 * 32 + sk];
                xkr[m] = v * wk[f0 * 32 + sk];
                xvr[m] = v * wv[f0 * 32 + sk];
            } else { xkr[m] = 0.f; xvr[m] = 0.f; }
        }
    };
    auto zacc = [&]() {
        #pragma unroll
        for (int nt = 0; nt < 7; ++nt)
            #pragma unroll
            for (int r = 0; r < 16; ++r) acc[nt][r] = 0.f;
    };

    // one fi: softmax in-registers -> A-frags via shfl_xor(32) -> 21 MFMA
    auto do_fi = [&](float q, const u16* __restrict__ bp, int G, int g0) {
        float e[24], d = 0.f;
        #pragma unroll
        for (int m = 0; m < 24; ++m) { e[m] = __expf(xkr[m] * q); d += e[m]; }
        if (sh) d -= 8.0f;            // pads (xk=0 -> e=1) excluded from denom
        d += __shfl_xor(d, 32);
        const float r = 1.0f / d;
        u32 pk[12];
        #pragma unroll
        for (int p = 0; p < 12; ++p)
            pk[p] = (u32)f2bf(e[2*p] * r * xvr[2*p])
                  | ((u32)f2bf(e[2*p+1] * r * xvr[2*p+1]) << 16);
        u32 tmp[4];
        #pragma unroll
        for (int j = 0; j < 4; ++j) tmp[j] = (u32)__shfl_xor((int)pk[4 + j], 32);
        #pragma unroll
        for (int s = 0; s < 3; ++s) {
            u32 a4[4];
            #pragma unroll
            for (int j = 0; j < 4; ++j)
                a4[j] = (s == 0) ? (hb ? tmp[j] : pk[j])
                      : (s == 1) ? (hb ? pk[j] : pk[8 + j])
                                 : (hb ? pk[8 + j] : tmp[j]);
            bf16x8 av;
            __builtin_memcpy(&av, a4, 16);
            const u16* bgp = bp + ((size_t)(g0 + s) * 64 + lane) * 8;
            #pragma unroll
            for (int nt = 0; nt < 7; ++nt) {
                bf16x8 bv = *reinterpret_cast<const bf16x8*>(bgp + (size_t)nt * G * 512);
                acc[nt] = __builtin_amdgcn_mfma_f32_32x32x16_bf16(av, bv, acc[nt], 0, 0, 0);
            }
        }
    };

    // ---------------- layer 0 ----------------
    load_xw(wk0, wv0);
    zacc();
    for (int t = 0; t < 5; ++t) {
        const int fi = wid + t * 8;
        const float q = x0[(size_t)b * 1280 + fi * 32 + sk] * wq0[fi * 32 + sk];
        do_fi(q, bp0, G0, fi * 3);
    }
    __syncthreads();                       // zeros done before atomics
    #pragma unroll
    for (int nt = 0; nt < 7; ++nt) {
        const int j = nt * 32 + sk;
        if (j < NJ) {
            #pragma unroll
            for (int r = 0; r < 16; ++r) {
                const int k = (r & 3) + 8 * (r >> 2) + 4 * sh;
                atomicAdd(&s_res[j][k], acc[nt][r]);
            }
        }
    }
    __syncthreads();

    // out[b, 0:200] = sum_k res
    if (tid < NJ) {
        float s = 0.f;
        #pragma unroll
        for (int k = 0; k < 32; ++k) s += s_res[tid][k];
        out[(size_t)b * 400 + tid] = s;
    }

    // ---------------- layer 1 ----------------
    load_xw(wk1, wv1);
    zacc();
    for (int t = 0; t < 25; ++t) {
        const int fi = wid + t * 8;
        const float q = s_res[fi][sk] * wq1[fi * 32 + sk];
        do_fi(q, bp1, G1, fi * 3);
    }
    // k-sum per (wave, nt): 16 regs cover 16 of 32 k-rows; +partner half
    #pragma unroll
    for (int nt = 0; nt < 7; ++nt) {
        float s = 0.f;
        #pragma unroll
        for (int r = 0; r < 16; ++r) s += acc[nt][r];
        s += __shfl_xor(s, 32);
        const int j = nt * 32 + sk;
        if (!hb && j < NJ) atomicAdd(&s_o1[j], s);
    }
    __syncthreads();
    if (tid < NJ) out[(size_t)b * 400 + 200 + tid] = s_o1[tid];
}

extern "C" void kernel_launch(void* const* d_in, const int* in_sizes, int n_in,
                              void* d_out, int out_size, void* d_ws, size_t ws_size,
                              hipStream_t stream) {
    const float* x0  = (const float*)d_in[0];
    const float* wq0 = (const float*)d_in[1];
    const float* wk0 = (const float*)d_in[2];
    const float* wv0 = (const float*)d_in[3];
    const float* cw0 = (const float*)d_in[4];
    const float* wq1 = (const float*)d_in[5];
    const float* wk1 = (const float*)d_in[6];
    const float* wv1 = (const float*)d_in[7];
    const float* cw1 = (const float*)d_in[8];
    float* out = (float*)d_out;

    char* ws = (char*)d_ws;
    u16* bp0 = (u16*)ws;                    // 7*120*512*2 =   860,160 B
    u16* bp1 = (u16*)(ws + 860160);         // 7*600*512*2 = 4,300,800 B

    pack_b<40> <<<dim3(40, 7),  256, 0, stream>>>(cw0, bp0);
    pack_b<200><<<dim3(200, 7), 256, 0, stream>>>(cw1, bp1);

    cin_fused<<<256, NTHR, 0, stream>>>(x0, wq0, wk0, wv0,
                                        wq1, wk1, wv1, bp0, bp1, out);
}